// Round 10
// baseline (147.745 us; speedup 1.0000x reference)
//
#include <hip/hip_runtime.h>
#include <cstdint>

#define FP8MAX 448.0f

typedef float f32x4 __attribute__((ext_vector_type(4)));
typedef int   i32x4 __attribute__((ext_vector_type(4)));
typedef int   i32x8 __attribute__((ext_vector_type(8)));

union frag8 { i32x8 v8; i32x4 v4[2]; };

__device__ __forceinline__ void gload_lds16(const void* g, void* l) {
  __builtin_amdgcn_global_load_lds(
      (const __attribute__((address_space(1))) unsigned int*)g,
      (__attribute__((address_space(3))) unsigned int*)l,
      16, 0, 0);
}

// ---------- quantize x rows: H=2048 floats -> fp8 bytes + per-128-group inv_scale ----------
__global__ __launch_bounds__(256) void quant_x(const float* __restrict__ x,
                                               uint8_t* __restrict__ xq,
                                               float* __restrict__ sa) {
  const int m = blockIdx.x;
  const int t = threadIdx.x;
  const float* xr = x + (size_t)m * 2048;
  float4 v0 = ((const float4*)xr)[t * 2];
  float4 v1 = ((const float4*)xr)[t * 2 + 1];
  float amax = fmaxf(fmaxf(fmaxf(fabsf(v0.x), fabsf(v0.y)), fmaxf(fabsf(v0.z), fabsf(v0.w))),
                     fmaxf(fmaxf(fabsf(v1.x), fabsf(v1.y)), fmaxf(fabsf(v1.z), fabsf(v1.w))));
  #pragma unroll
  for (int off = 1; off < 16; off <<= 1)
    amax = fmaxf(amax, __shfl_xor(amax, off));
  amax = fmaxf(amax, 1e-12f);
  float s   = FP8MAX / amax;   // same op order as reference
  float inv = 1.0f / s;
  if ((t & 15) == 0) sa[(size_t)m * 16 + (t >> 4)] = inv;
  float q[8] = {v0.x * s, v0.y * s, v0.z * s, v0.w * s,
                v1.x * s, v1.y * s, v1.z * s, v1.w * s};
  #pragma unroll
  for (int i = 0; i < 8; ++i) q[i] = fminf(fmaxf(q[i], -FP8MAX), FP8MAX);
  union { unsigned long long u; unsigned int w[2]; } pk;
  pk.w[0] = __builtin_amdgcn_cvt_pk_fp8_f32(q[0], q[1], 0, false);
  pk.w[0] = __builtin_amdgcn_cvt_pk_fp8_f32(q[2], q[3], pk.w[0], true);
  pk.w[1] = __builtin_amdgcn_cvt_pk_fp8_f32(q[4], q[5], 0, false);
  pk.w[1] = __builtin_amdgcn_cvt_pk_fp8_f32(q[6], q[7], pk.w[1], true);
  ((unsigned long long*)(xq + (size_t)m * 2048))[t] = pk.u;
}

// ---------- weight f32 -> fp8, FRAGMENT-PACKED layout ----------
// Layout: [O/16][J=H/128][c=0..7][r=0..15][16B]; (o,kb) -> o-row block ob=o>>4,
// r=o&15, j=kb>>7, c=(kb>>4)&7. One dwordx4 over lanes r16=0..15 reads 256B
// contiguous (coalesced B-fragment loads in the GEMM).
__global__ __launch_bounds__(256) void conv_w(const float* __restrict__ w,
                                              uint8_t* __restrict__ w8r,
                                              int n8, int H) {
  int i = blockIdx.x * 256 + threadIdx.x;
  if (i >= n8) return;
  float4 v0 = ((const float4*)w)[i * 2];
  float4 v1 = ((const float4*)w)[i * 2 + 1];
  union { unsigned long long u; unsigned int x[2]; } pk;
  pk.x[0] = __builtin_amdgcn_cvt_pk_fp8_f32(v0.x, v0.y, 0, false);
  pk.x[0] = __builtin_amdgcn_cvt_pk_fp8_f32(v0.z, v0.w, pk.x[0], true);
  pk.x[1] = __builtin_amdgcn_cvt_pk_fp8_f32(v1.x, v1.y, 0, false);
  pk.x[1] = __builtin_amdgcn_cvt_pk_fp8_f32(v1.z, v1.w, pk.x[1], true);
  const int hb = H >> 3;               // threads per row
  int o  = i / hb;
  int kb = (i - o * hb) * 8;           // first k-byte (multiple of 8)
  const int J = H >> 7;
  size_t dst = ((((size_t)(o >> 4) * J + (kb >> 7)) * 8 + ((kb >> 4) & 7)) << 8)
             + ((o & 15) << 4) + (kb & 15);
  *(unsigned long long*)(w8r + dst) = pk.u;
}

// ---------- block-scaled fp8 GEMM: BM=BN=BK=128, 256 thr = 4 waves (2x2),
// 64x64 per wave. A: gload_lds + XOR swizzle, dbuf, staged 2-ahead.
// B: global->register from fragment-packed w8r (L1/L2-hot, coalesced).
// LDS 40KB, 2 blocks/CU. Compiler-inserted waits do the vmcnt ordering. ----------
__global__ __launch_bounds__(256, 2) void gemm_fp8(
    const uint8_t* __restrict__ A, const uint8_t* __restrict__ Br,
    const float* __restrict__ sa, const float* __restrict__ sb,
    const float* __restrict__ bias, float* __restrict__ out,
    int M, int N, int K) {
  const int J = K >> 7;               // 16
  const int nbn = N >> 7;             // 16
  int bid = blockIdx.x;
  int nwg = gridDim.x;
  if ((nwg & 7) == 0) {               // T1 XCD chunked swizzle
    int cpx = nwg >> 3;
    bid = (bid & 7) * cpx + (bid >> 3);
  }
  const int bn = bid % nbn;
  const int bm = bid / nbn;
  const int t = threadIdx.x;
  const int lane = t & 63;
  const int w = t >> 6;
  const int wm = (w >> 1) << 6;       // wave M offset (0/64)
  const int wn = (w & 1) << 6;        // wave N offset (0/64)
  const int r16 = lane & 15;
  const int kg = lane >> 4;

  __shared__ __align__(16) uint8_t lA[2][128 * 128];   // 32 KB
  __shared__ __align__(16) float sal[16 * 128];        // 8 KB, [j][row]

  const uint8_t* gA = A + (size_t)bm * 128 * K;

  // conflict-free sal staging: consecutive lanes -> consecutive LDS words
  for (int i = t; i < 128 * 16; i += 256) {
    int row = i & 127, j = i >> 7;
    sal[j * 128 + row] = sa[((size_t)bm * 128 + row) * 16 + j];
  }

  const int srow = t >> 3;     // 0..31
  const int sg = t & 7;        // 16B segment

  // stage one A K-tile (16KB): 4 gload_lds per thread (4 vmcnt units)
  #define STAGEA(buf_, kt_) do {                                             \
    _Pragma("unroll")                                                        \
    for (int it_ = 0; it_ < 2; ++it_) {                                      \
      int r_ = srow + it_ * 32;                                              \
      int so_ = ((sg ^ (r_ & 7)) << 4);                                      \
      gload_lds16(gA + (size_t)r_ * K + ((kt_) << 7) + so_,                  \
                  &lA[buf_][r_ * 128 + sg * 16]);                            \
      int r2_ = r_ + 64;                                                     \
      int so2_ = ((sg ^ (r2_ & 7)) << 4);                                    \
      gload_lds16(gA + (size_t)r2_ * K + ((kt_) << 7) + so2_,                \
                  &lA[buf_][r2_ * 128 + sg * 16]);                           \
    } } while (0)

  __syncthreads();   // sal visible; drains sal's global loads

  STAGEA(0, 0);      // 4 outstanding
  STAGEA(1, 1);      // 8 outstanding

  f32x4 tot[4][4] = {};
  const f32x4 fz = {0.f, 0.f, 0.f, 0.f};
  frag8 av[4], bv[4];
  f32x4 scq[4];

  int rowA[4];
  #pragma unroll
  for (int a = 0; a < 4; ++a) rowA[a] = wm + a * 16 + r16;

  // B fragment bases (fragment-packed layout): frag b, reg-half h at
  // bBase[b] + kt*2048 + h*256
  const uint8_t* bBase[4];
  #pragma unroll
  for (int b = 0; b < 4; ++b) {
    int ob = bn * 8 + (wn >> 4) + b;
    bBase[b] = Br + (size_t)ob * J * 2048 + kg * 512 + r16 * 16;
  }

  // A(0) resident before first reads (leave A(1) in flight)
  asm volatile("s_waitcnt vmcnt(4)" ::: "memory");
  __builtin_amdgcn_s_barrier();
  asm volatile("" ::: "memory");

  const int KT = K >> 7;   // 16
  for (int kt = 0; kt < KT; ++kt) {
    const int cur = kt & 1;
    // B fragments: global -> regs (coalesced 256B runs; L1/L2-hot)
    #pragma unroll
    for (int b = 0; b < 4; ++b) {
      const uint8_t* p = bBase[b] + ((size_t)kt << 11);
      bv[b].v4[0] = *(const i32x4*)p;
      bv[b].v4[1] = *(const i32x4*)(p + 256);
    }
    // A fragments from LDS + scales
    #pragma unroll
    for (int a = 0; a < 4; ++a) {
      const int sw = (rowA[a] & 7) << 4;
      const uint8_t* bp = &lA[cur][rowA[a] * 128];
      av[a].v4[0] = *(const i32x4*)(bp + ((kg * 32) ^ sw));
      av[a].v4[1] = *(const i32x4*)(bp + ((kg * 32 + 16) ^ sw));
    }
    const float sbj = sb[bn * J + kt];
    #pragma unroll
    for (int a = 0; a < 4; ++a)
      scq[a] = (*(const f32x4*)&sal[kt * 128 + wm + a * 16 + kg * 4]) * sbj;
    // 16 MX MFMA + fused rescale (compiler inserts vmcnt/lgkm waits for
    // bv/av; that drain also retires the A-stage issued a full iter ago,
    // which is what makes next iter's barrier-visibility sound)
    #pragma unroll
    for (int a = 0; a < 4; ++a) {
      #pragma unroll
      for (int b = 0; b < 4; ++b) {
        f32x4 p = __builtin_amdgcn_mfma_scale_f32_16x16x128_f8f6f4(
            av[a].v8, bv[b].v8, fz, 0, 0, 0, 0x7f7f7f7f, 0, 0x7f7f7f7f);
        tot[a][b] += p * scq[a];
      }
    }
    __builtin_amdgcn_s_barrier();      // all waves done reading buf[cur]
    asm volatile("" ::: "memory");
    // stage A(kt+2) into buf[cur]; wrapped junk on last 2 iters (WAR-safe)
    const int kt2 = (kt + 2 < KT) ? kt + 2 : kt + 2 - KT;
    STAGEA(cur, kt2);
    __builtin_amdgcn_s_barrier();      // entry barrier of next iteration
    asm volatile("" ::: "memory");
  }
  asm volatile("s_waitcnt vmcnt(0)" ::: "memory");   // retire junk ring loads

  // epilogue: bias + store (C/D: col = r16, row = kg*4 + r)
  float bb[4];
  #pragma unroll
  for (int b = 0; b < 4; ++b) bb[b] = bias[bn * 128 + wn + b * 16 + r16];
  #pragma unroll
  for (int a = 0; a < 4; ++a) {
    int row0 = bm * 128 + wm + a * 16 + kg * 4;
    #pragma unroll
    for (int r = 0; r < 4; ++r) {
      float* orow = out + (size_t)(row0 + r) * N + bn * 128;
      #pragma unroll
      for (int b = 0; b < 4; ++b)
        orow[wn + b * 16 + r16] = tot[a][b][r] + bb[b];
    }
  }
}

extern "C" void kernel_launch(void* const* d_in, const int* in_sizes, int n_in,
                              void* d_out, int out_size, void* d_ws, size_t ws_size,
                              hipStream_t stream) {
  const float* x    = (const float*)d_in[0];
  const float* wt   = (const float*)d_in[1];
  const float* wsc  = (const float*)d_in[2];
  const float* bias = (const float*)d_in[3];
  float* out = (float*)d_out;

  const int O = in_sizes[3];            // 2048
  const int H = in_sizes[1] / O;        // 2048
  const int M = in_sizes[0] / H;        // 16384

  uint8_t* xq  = (uint8_t*)d_ws;                      // M*H bytes (row-major)
  uint8_t* w8r = xq + (size_t)M * H;                  // O*H bytes (fragment-packed)
  float*   sa  = (float*)(w8r + (size_t)O * H);       // M*(H/128) floats

  quant_x<<<M, 256, 0, stream>>>(x, xq, sa);
  int n8 = O * H / 8;
  conv_w<<<(n8 + 255) / 256, 256, 0, stream>>>(wt, w8r, n8, H);
  int grid = (M / 128) * (O / 128);
  gemm_fp8<<<grid, 256, 0, stream>>>(xq, w8r, sa, wsc, bias, out, M, O, H);
}